// Round 10
// baseline (67.364 us; speedup 1.0000x reference)
//
#include <hip/hip_runtime.h>
#include <math.h>

#define T_STEPS 1000000
#define BLOCK 256
#define EPT 8                                // elements per thread
#define CHUNK (BLOCK * EPT)                  // 2048
#define NB ((T_STEPS + CHUNK - 1) / CHUNK)   // 489 blocks
#define NF4 (T_STEPS / 2)                    // 500000 float4 of controls
#define NWAVE (BLOCK / 64)                   // 4
#define MPER ((NB + BLOCK - 1) / BLOCK)      // 2 aggregates/thread in combine

typedef unsigned int uint;

// ---- block scan helpers (fp64, shfl + 4-partial LDS) --------------------

__device__ __forceinline__ double waveScanIncl(double v) {
#pragma unroll
    for (int off = 1; off < 64; off <<= 1) {
        double x = __shfl_up(v, off, 64);
        if ((threadIdx.x & 63) >= off) v += x;
    }
    return v;
}

__device__ __forceinline__ double blockScanEx(double v, double* sw, double* tot) {
    const int lane = threadIdx.x & 63, w = threadIdx.x >> 6;
    double inc = waveScanIncl(v);
    if (lane == 63) sw[w] = inc;
    __syncthreads();
    double w0 = sw[0], w1 = sw[1], w2 = sw[2], w3 = sw[3];
    __syncthreads();
    *tot = w0 + w1 + w2 + w3;
    double woff = (w > 0 ? w0 : 0.0) + (w > 1 ? w1 : 0.0) + (w > 2 ? w2 : 0.0);
    return woff + inc - v;
}

// fp64 range reduction -> HW v_sin_f32/v_cos_f32 (abs err ~1e-6)
__device__ __forceinline__ void ftrig(double th, double& cs, double& sn) {
    const double INV2PI = 0.15915494309189535;
    double rev = th * INV2PI;
    double fr = rev - rint(rev);                 // [-0.5, 0.5]
    float x = (float)fr * 6.283185307179586f;
    sn = (double)__sinf(x);
    cs = (double)__cosf(x);
}

// ---- fused: local scan -> last-block combine -> flag -> output ----------
// NON-cooperative. Residency guarantee: __launch_bounds__(256,2) => VGPR
// cap 256 (kernel needs ~150, no spills) => >=2 blocks/CU => 512 slots >=
// 489 blocks, so every block is co-resident and the single-flag wait is
// deadlock-free. No block ever waits before publishing its aggregate.
// (R9 lesson: coop launch of 977 blocks silently failed its capacity
// check; R2 lesson: per-block O(b) spins + fences thrash cross-XCD L2 --
// here there is ONE poller lane per block on ONE flag.)

__global__ void __launch_bounds__(BLOCK, 2) k_fused(
    const float4* __restrict__ ctrl4, const float* __restrict__ sp,
    float4* __restrict__ out4, float* __restrict__ traj,
    uint* __restrict__ ctl,
    double* __restrict__ aggTh, double* __restrict__ aggA,
    double* __restrict__ aggB,
    double* __restrict__ entX, double* __restrict__ entY,
    double* __restrict__ entPsi) {
    __shared__ double sw[NWAVE];
    __shared__ double sent[3];
    __shared__ int s_last;
    const int b = blockIdx.x, t = threadIdx.x;
    const int f0 = b * (CHUNK / 2) + 4 * t;  // 4 consecutive float4 per thread

    // -- phase 1: load, passthrough, local rigid-motion scan --
    float4 c[4];
#pragma unroll
    for (int j = 0; j < 4; ++j) {
        int f = f0 + j;
        c[j] = (f < NF4) ? ctrl4[f] : make_float4(0.f, 0.f, 0.f, 0.f);
    }
#pragma unroll
    for (int j = 0; j < 4; ++j) {
        int f = f0 + j;
        if (f < NF4) out4[f] = c[j];  // controls passthrough output
    }

    double dth[EPT], spd[EPT];
#pragma unroll
    for (int j = 0; j < 4; ++j) {
        dth[2 * j]     = 10.0 * (double)c[j].y;
        dth[2 * j + 1] = 10.0 * (double)c[j].w;
        spd[2 * j]     = fabs((double)c[j].x);
        spd[2 * j + 1] = fabs((double)c[j].z);
    }
    double lth = 0.0;
#pragma unroll
    for (int k = 0; k < EPT; ++k) lth += dth[k];
    double thTot;
    const double thb = blockScanEx(lth, sw, &thTot);

    double av[EPT], bv[EPT];
    double la = 0.0, lb = 0.0;
    {
        double run = thb;
#pragma unroll
        for (int k = 0; k < EPT; ++k) {
            double cs, sn;
            ftrig(run, cs, sn);
            av[k] = spd[k] * cs;
            bv[k] = spd[k] * sn;
            la += av[k];
            lb += bv[k];
            run += dth[k];
        }
    }
    double aTot, bTot;
    const double Aex = blockScanEx(la, sw, &aTot);
    const double Bex = blockScanEx(lb, sw, &bTot);

    // -- publish aggregate; last arrival runs the combine --
    if (t == 0) {
        __hip_atomic_store(&aggTh[b], thTot, __ATOMIC_RELAXED, __HIP_MEMORY_SCOPE_AGENT);
        __hip_atomic_store(&aggA[b], aTot, __ATOMIC_RELAXED, __HIP_MEMORY_SCOPE_AGENT);
        __hip_atomic_store(&aggB[b], bTot, __ATOMIC_RELAXED, __HIP_MEMORY_SCOPE_AGENT);
        uint old = __hip_atomic_fetch_add(&ctl[0], 1u, __ATOMIC_ACQ_REL,
                                          __HIP_MEMORY_SCOPE_AGENT);
        s_last = (old == (uint)(NB - 1));
    }
    __syncthreads();

    if (s_last) {
        // combine: thread owns MPER contiguous aggregates (O(NB) total)
        double pTh[MPER], pA[MPER], pB[MPER];
        double mlth = 0.0;
#pragma unroll
        for (int k = 0; k < MPER; ++k) {
            int p = t * MPER + k;
            if (p < NB) {
                pTh[k] = __hip_atomic_load(&aggTh[p], __ATOMIC_RELAXED, __HIP_MEMORY_SCOPE_AGENT);
                pA[k]  = __hip_atomic_load(&aggA[p], __ATOMIC_RELAXED, __HIP_MEMORY_SCOPE_AGENT);
                pB[k]  = __hip_atomic_load(&aggB[p], __ATOMIC_RELAXED, __HIP_MEMORY_SCOPE_AGENT);
            } else {
                pTh[k] = pA[k] = pB[k] = 0.0;
            }
            mlth += pTh[k];
        }
        const double x0 = (double)sp[0], y0 = (double)sp[1], th00 = (double)sp[2];
        double mthTot;
        const double mthEx = blockScanEx(mlth, sw, &mthTot);

        double tx[MPER], ty[MPER], ps[MPER];
        double mlx = 0.0, mly = 0.0;
        {
            double run = th00 + mthEx;  // entry angle of aggregate t*MPER
#pragma unroll
            for (int k = 0; k < MPER; ++k) {
                ps[k] = run;
                double cs, sn;
                ftrig(run, cs, sn);
                tx[k] = cs * pA[k] - sn * pB[k];
                ty[k] = sn * pA[k] + cs * pB[k];
                mlx += tx[k];
                mly += ty[k];
                run += pTh[k];
            }
        }
        double xT, yT;
        double rx = x0 + blockScanEx(mlx, sw, &xT);
        double ry = y0 + blockScanEx(mly, sw, &yT);
#pragma unroll
        for (int k = 0; k < MPER; ++k) {
            int p = t * MPER + k;
            if (p < NB) {
                __hip_atomic_store(&entX[p], rx, __ATOMIC_RELAXED, __HIP_MEMORY_SCOPE_AGENT);
                __hip_atomic_store(&entY[p], ry, __ATOMIC_RELAXED, __HIP_MEMORY_SCOPE_AGENT);
                __hip_atomic_store(&entPsi[p], ps[k], __ATOMIC_RELAXED, __HIP_MEMORY_SCOPE_AGENT);
            }
            rx += tx[k];
            ry += ty[k];
        }
        __threadfence();  // drain entry stores to agent scope (one block, once)
        __syncthreads();
        if (t == 0)
            __hip_atomic_store(&ctl[1], 1u, __ATOMIC_RELEASE, __HIP_MEMORY_SCOPE_AGENT);
    }

    // -- wait: ONE poller lane per block on ONE flag, coarse backoff --
    if (t == 0) {
        while (__hip_atomic_load(&ctl[1], __ATOMIC_ACQUIRE,
                                 __HIP_MEMORY_SCOPE_AGENT) == 0u)
            __builtin_amdgcn_s_sleep(8);
        sent[0] = __hip_atomic_load(&entX[b], __ATOMIC_RELAXED, __HIP_MEMORY_SCOPE_AGENT);
        sent[1] = __hip_atomic_load(&entY[b], __ATOMIC_RELAXED, __HIP_MEMORY_SCOPE_AGENT);
        sent[2] = __hip_atomic_load(&entPsi[b], __ATOMIC_RELAXED, __HIP_MEMORY_SCOPE_AGENT);
    }
    __syncthreads();

    // -- phase 2: finish from registers retained across the wait --
    const double Xin = sent[0], Yin = sent[1], psi = sent[2];
    double cps, sps;
    ftrig(psi, cps, sps);

    const long i0 = (long)b * CHUNK + (long)EPT * t;  // first owned element
    double Ar = Aex, Br = Bex, run = thb;
#pragma unroll
    for (int k = 0; k < EPT; ++k) {
        Ar += av[k];
        Br += bv[k];
        run += dth[k];
        long i = i0 + k;
        if (i < T_STEPS) {
            float* p = traj + 3 * (i + 1);
            p[0] = (float)(Xin + cps * Ar - sps * Br);
            p[1] = (float)(Yin + sps * Ar + cps * Br);
            p[2] = (float)(psi + run);
        }
    }
    if (b == 0 && t == 0) {
        traj[0] = sp[0];
        traj[1] = sp[1];
        traj[2] = sp[2];
    }
}

// ---- launch --------------------------------------------------------------

extern "C" void kernel_launch(void* const* d_in, const int* in_sizes, int n_in,
                              void* d_out, int out_size, void* d_ws, size_t ws_size,
                              hipStream_t stream) {
    const float*  start_pose = (const float*)d_in[0];
    const float4* ctrl4      = (const float4*)d_in[1];

    float*  out  = (float*)d_out;
    float4* out4 = (float4*)out;                 // controls passthrough
    float*  traj = out + 2 * (long)T_STEPS;      // (T+1, 3)

    char* ws = (char*)d_ws;
    uint*   ctl    = (uint*)ws;                  // [0]=arrival counter, [1]=flag
    double* aggTh  = (double*)(ws + 64);
    double* aggA   = aggTh + NB;
    double* aggB   = aggA + NB;
    double* entX   = aggB + NB;
    double* entY   = entX + NB;
    double* entPsi = entY + NB;

    // zero the two control words (ws is poisoned, never re-zeroed by harness)
    hipMemsetAsync(ctl, 0, 2 * sizeof(uint), stream);

    hipLaunchKernelGGL(k_fused, dim3(NB), dim3(BLOCK), 0, stream,
                       ctrl4, start_pose, out4, traj, ctl,
                       aggTh, aggA, aggB, entX, entY, entPsi);
}

// Round 11
// 23.956 us; speedup vs baseline: 2.8120x; 2.8120x over previous
//
#include <hip/hip_runtime.h>
#include <math.h>

#define T_STEPS 1000000
#define BLOCK 512
#define EPT 4                                // elements per thread
#define CHUNK (BLOCK * EPT)                  // 2048
#define NB ((T_STEPS + CHUNK - 1) / CHUNK)   // 489 blocks
#define NF4 (T_STEPS / 2)                    // 500000 float4 of controls
#define NWAVE (BLOCK / 64)                   // 8

// ---- block scan helpers (fp64, shfl + 8-partial LDS) --------------------

__device__ __forceinline__ double waveScanIncl(double v) {
#pragma unroll
    for (int off = 1; off < 64; off <<= 1) {
        double x = __shfl_up(v, off, 64);
        if ((threadIdx.x & 63) >= off) v += x;
    }
    return v;
}

// exclusive prefix over per-thread values; *tot = block total
__device__ __forceinline__ double blockScanEx(double v, double* sw, double* tot) {
    const int lane = threadIdx.x & 63, w = threadIdx.x >> 6;
    double inc = waveScanIncl(v);
    if (lane == 63) sw[w] = inc;
    __syncthreads();
    double woff = 0.0, T = 0.0;
#pragma unroll
    for (int i = 0; i < NWAVE; ++i) {
        double x = sw[i];
        T += x;
        if (i < w) woff += x;
    }
    __syncthreads();
    *tot = T;
    return woff + inc - v;
}

__device__ __forceinline__ double blockSum(double v, double* sw) {
#pragma unroll
    for (int off = 32; off > 0; off >>= 1) v += __shfl_xor(v, off, 64);
    const int lane = threadIdx.x & 63, w = threadIdx.x >> 6;
    if (lane == 0) sw[w] = v;
    __syncthreads();
    double r = 0.0;
#pragma unroll
    for (int i = 0; i < NWAVE; ++i) r += sw[i];
    __syncthreads();
    return r;
}

// fp64 range reduction -> HW v_sin_f32/v_cos_f32 (abs err ~1e-6)
__device__ __forceinline__ void ftrig(double th, double& cs, double& sn) {
    const double INV2PI = 0.15915494309189535;
    double rev = th * INV2PI;
    double fr = rev - rint(rev);                 // [-0.5, 0.5]
    float x = (float)fr * 6.283185307179586f;
    sn = (double)__sinf(x);
    cs = (double)__cosf(x);
}

// ---- K1: controls passthrough + per-segment rigid-motion aggregates -----
// Aggregate of segment p (entry angle unknown): Theta = sum dth,
// A = sum s*cos(phi_local), B = sum s*sin(phi_local).
// 512-thread blocks: 8 waves/block -> ~48% occupancy at 489 blocks
// (R3/R4 ran 4-wave blocks at ~20% and were latency-bound). VGPR cap 128
// via (512,4); EPT=4 live set ~70 regs -> no spills (R5/R6 lesson).

__global__ void __launch_bounds__(BLOCK, 4) k_agg(
    const float4* __restrict__ ctrl4, float4* __restrict__ out4,
    double* __restrict__ aggTh, double* __restrict__ aggA,
    double* __restrict__ aggB) {
    __shared__ double sw[NWAVE];
    const int b = blockIdx.x, t = threadIdx.x;
    const int f0 = b * (CHUNK / 2) + 2 * t;  // two consecutive float4

    float4 ca = (f0 < NF4) ? ctrl4[f0] : make_float4(0.f, 0.f, 0.f, 0.f);
    float4 cb = (f0 + 1 < NF4) ? ctrl4[f0 + 1] : make_float4(0.f, 0.f, 0.f, 0.f);
    if (f0 < NF4) out4[f0] = ca;
    if (f0 + 1 < NF4) out4[f0 + 1] = cb;

    const double dth0 = 10.0 * (double)ca.y, dth1 = 10.0 * (double)ca.w;
    const double dth2 = 10.0 * (double)cb.y, dth3 = 10.0 * (double)cb.w;
    double thTot;
    const double thb = blockScanEx(dth0 + dth1 + dth2 + dth3, sw, &thTot);

    // 4 INDEPENDENT angles (prefix adds first, then parallel trig — no
    // serial accumulate-then-trig chain)
    const double g0 = thb;
    const double g1 = thb + dth0;
    const double g2 = g1 + dth1;
    const double g3 = g2 + dth2;
    double c0, n0, c1, n1, c2, n2, c3, n3;
    ftrig(g0, c0, n0);
    ftrig(g1, c1, n1);
    ftrig(g2, c2, n2);
    ftrig(g3, c3, n3);
    const double s0 = fabs((double)ca.x), s1 = fabs((double)ca.z);
    const double s2 = fabs((double)cb.x), s3 = fabs((double)cb.z);
    const double la = s0 * c0 + s1 * c1 + s2 * c2 + s3 * c3;
    const double lb = s0 * n0 + s1 * n1 + s2 * n2 + s3 * n3;

    const double aTot = blockSum(la, sw);
    const double bTot = blockSum(lb, sw);
    if (t == 0) {
        aggTh[b] = thTot;
        aggA[b]  = aTot;
        aggB[b]  = bTot;
    }
}

// ---- K2: compose (1 aggregate/thread), redo local scan, write traj ------

__global__ void __launch_bounds__(BLOCK, 4) k_out(
    const float4* __restrict__ ctrl4, const float* __restrict__ sp,
    const double* __restrict__ aggTh, const double* __restrict__ aggA,
    const double* __restrict__ aggB, float* __restrict__ traj) {
    __shared__ double sw[NWAVE];
    const int b = blockIdx.x, t = threadIdx.x;
    const int f0 = b * (CHUNK / 2) + 2 * t;

    // issue controls loads first: HBM latency hides under the compose phase
    float4 ca = (f0 < NF4) ? ctrl4[f0] : make_float4(0.f, 0.f, 0.f, 0.f);
    float4 cb = (f0 + 1 < NF4) ? ctrl4[f0 + 1] : make_float4(0.f, 0.f, 0.f, 0.f);

    const double x0 = (double)sp[0], y0 = (double)sp[1], th0 = (double)sp[2];

    // -- compose: thread t owns aggregate t (t < NB) --
    double pTh = 0.0, pA = 0.0, pB = 0.0;
    if (t < NB) {
        pTh = aggTh[t];
        pA  = aggA[t];
        pB  = aggB[t];
    }
    double aggTot;
    const double exTh = blockScanEx(pTh, sw, &aggTot);  // theta entry of agg t

    double tx = 0.0, ty = 0.0;
    if (t < NB) {
        double cs, sn;
        ftrig(th0 + exTh, cs, sn);
        tx = cs * pA - sn * pB;
        ty = sn * pA + cs * pB;
    }
    const double Xin = x0 + blockSum((t < b) ? tx : 0.0, sw);
    const double Yin = y0 + blockSum((t < b) ? ty : 0.0, sw);
    const double psi = th0 + blockSum((t < b) ? pTh : 0.0, sw);
    double cps, sps;
    ftrig(psi, cps, sps);

    // -- local scan (same as K1) --
    const double dth0 = 10.0 * (double)ca.y, dth1 = 10.0 * (double)ca.w;
    const double dth2 = 10.0 * (double)cb.y, dth3 = 10.0 * (double)cb.w;
    double thTot;
    const double thb = blockScanEx(dth0 + dth1 + dth2 + dth3, sw, &thTot);

    const double g0 = thb;
    const double g1 = thb + dth0;
    const double g2 = g1 + dth1;
    const double g3 = g2 + dth2;
    double c0, n0, c1, n1, c2, n2, c3, n3;
    ftrig(g0, c0, n0);
    ftrig(g1, c1, n1);
    ftrig(g2, c2, n2);
    ftrig(g3, c3, n3);
    const double s0 = fabs((double)ca.x), s1 = fabs((double)ca.z);
    const double s2 = fabs((double)cb.x), s3 = fabs((double)cb.z);
    const double av0 = s0 * c0, bv0 = s0 * n0;
    const double av1 = s1 * c1, bv1 = s1 * n1;
    const double av2 = s2 * c2, bv2 = s2 * n2;
    const double av3 = s3 * c3, bv3 = s3 * n3;

    double aTot, bTot;
    const double Aex = blockScanEx(av0 + av1 + av2 + av3, sw, &aTot);
    const double Bex = blockScanEx(bv0 + bv1 + bv2 + bv3, sw, &bTot);

    const double A1 = Aex + av0, B1 = Bex + bv0;
    const double A2 = A1 + av1,  B2 = B1 + bv1;
    const double A3 = A2 + av2,  B3 = B2 + bv2;
    const double A4 = A3 + av3,  B4 = B3 + bv3;
    const double h1 = g1, h2 = g2, h3 = g3, h4 = g3 + dth3;  // incl. theta

    // -- write rows i0+1 .. i0+4 (12 contiguous floats) --
    const long i0 = (long)b * CHUNK + 4L * t;
    float* p = traj + 3 * (i0 + 1);
    if (i0 + 3 < T_STEPS) {  // fast path: all 4 rows in range
        p[0]  = (float)(Xin + cps * A1 - sps * B1);
        p[1]  = (float)(Yin + sps * A1 + cps * B1);
        p[2]  = (float)(psi + h1);
        p[3]  = (float)(Xin + cps * A2 - sps * B2);
        p[4]  = (float)(Yin + sps * A2 + cps * B2);
        p[5]  = (float)(psi + h2);
        p[6]  = (float)(Xin + cps * A3 - sps * B3);
        p[7]  = (float)(Yin + sps * A3 + cps * B3);
        p[8]  = (float)(psi + h3);
        p[9]  = (float)(Xin + cps * A4 - sps * B4);
        p[10] = (float)(Yin + sps * A4 + cps * B4);
        p[11] = (float)(psi + h4);
    } else {
        if (i0 < T_STEPS) {
            p[0] = (float)(Xin + cps * A1 - sps * B1);
            p[1] = (float)(Yin + sps * A1 + cps * B1);
            p[2] = (float)(psi + h1);
        }
        if (i0 + 1 < T_STEPS) {
            p[3] = (float)(Xin + cps * A2 - sps * B2);
            p[4] = (float)(Yin + sps * A2 + cps * B2);
            p[5] = (float)(psi + h2);
        }
        if (i0 + 2 < T_STEPS) {
            p[6] = (float)(Xin + cps * A3 - sps * B3);
            p[7] = (float)(Yin + sps * A3 + cps * B3);
            p[8] = (float)(psi + h3);
        }
    }
    if (b == 0 && t == 0) {
        traj[0] = sp[0];
        traj[1] = sp[1];
        traj[2] = sp[2];
    }
}

// ---- launch --------------------------------------------------------------

extern "C" void kernel_launch(void* const* d_in, const int* in_sizes, int n_in,
                              void* d_out, int out_size, void* d_ws, size_t ws_size,
                              hipStream_t stream) {
    const float*  start_pose = (const float*)d_in[0];
    const float4* ctrl4      = (const float4*)d_in[1];

    float*  out  = (float*)d_out;
    float4* out4 = (float4*)out;                 // controls passthrough
    float*  traj = out + 2 * (long)T_STEPS;      // (T+1, 3)

    double* aggTh = (double*)d_ws;
    double* aggA  = aggTh + NB;
    double* aggB  = aggA + NB;

    hipLaunchKernelGGL(k_agg, dim3(NB), dim3(BLOCK), 0, stream,
                       ctrl4, out4, aggTh, aggA, aggB);
    hipLaunchKernelGGL(k_out, dim3(NB), dim3(BLOCK), 0, stream,
                       ctrl4, start_pose, aggTh, aggA, aggB, traj);
}